// Round 5
// baseline (2343.977 us; speedup 1.0000x reference)
//
#include <hip/hip_runtime.h>

typedef __bf16 bf16x8 __attribute__((ext_vector_type(8)));
typedef float f32x4 __attribute__((ext_vector_type(4)));
typedef unsigned u32x4 __attribute__((ext_vector_type(4)));
typedef unsigned short u16;

constexpr int T = 256, B = 64, D = 512, H = 1024;
constexpr int G4 = 4 * H;
constexpr int NBLK = 256;   // 2 layers x 2 batch-halves x 64 col-blocks (1/CU)
constexpr int NTHR = 256;   // 4 waves; wave = one K-quarter, all 4 gates
constexpr int BS = 32;      // batches per block
constexpr int MT = 2;       // 16-row MFMA tiles per block

__device__ __forceinline__ u16 f2bf(float f) {
  unsigned u = __builtin_bit_cast(unsigned, f);
  u += 0x7fffu + ((u >> 16) & 1u);
  return (u16)(u >> 16);
}

__device__ __forceinline__ f32x4 mfma16(bf16x8 a, bf16x8 b, f32x4 c) {
  return __builtin_amdgcn_mfma_f32_16x16x32_bf16(a, b, c, 0, 0, 0);
}

// fast saturating transcendentals (v_exp_f32 + v_rcp_f32; no NaN at +-inf)
__device__ __forceinline__ float sigm(float x) {
  return __builtin_amdgcn_rcpf(1.f + __expf(-x));
}
__device__ __forceinline__ float tanhfast(float x) {
  return 1.f - 2.f * __builtin_amdgcn_rcpf(__expf(2.f * x) + 1.f);
}

__device__ __forceinline__ int ldflag(const int* f, int i) {
  return __hip_atomic_load(&f[i], __ATOMIC_RELAXED, __HIP_MEMORY_SCOPE_AGENT);
}

// ---------------- prep kernels ----------------
__global__ void cvt_bf16(const float* __restrict__ src, u16* __restrict__ dst, int n4) {
  int i = blockIdx.x * blockDim.x + threadIdx.x;
  int st = gridDim.x * blockDim.x;
  for (; i < n4; i += st) {
    float4 v = reinterpret_cast<const float4*>(src)[i];
    ushort4 o;
    o.x = f2bf(v.x); o.y = f2bf(v.y); o.z = f2bf(v.z); o.w = f2bf(v.w);
    reinterpret_cast<ushort4*>(dst)[i] = o;
  }
}

__global__ void init_state(const float* __restrict__ h0,
                           u16* __restrict__ xs1, u16* __restrict__ h1buf,
                           const float* __restrict__ bih0, const float* __restrict__ bhh0,
                           const float* __restrict__ bih1, const float* __restrict__ bhh1,
                           float* __restrict__ bias0, float* __restrict__ bias1,
                           int* __restrict__ flags) {
  int i = blockIdx.x * blockDim.x + threadIdx.x;
  // per-wave flags: 2 per block. L0 entries (i<256) start 0; L1 entries start 1
  // ("h1b[0] = initial state is ready") so L1's first step needs no posts.
  if (i < 2 * NBLK) flags[i] = (i >= 2 * 128) ? 1 : 0;
  if (i < 2 * B * H) {
    int l = i / (B * H), rem = i % (B * H);
    int b = rem / H, k = rem % H;
    u16 v = f2bf(h0[(size_t)b * 2 * H + (size_t)l * H + k]);
    if (l == 0) xs1[(size_t)b * H + k] = v;
    else        h1buf[(size_t)b * H + k] = v;
  }
  if (i < G4) {
    bias0[i] = bih0[i] + bhh0[i];
    bias1[i] = bih1[i] + bhh1[i];
  }
}

// ---------------- persistent pipelined LSTM ----------------
// Logical block lb = g*64 + c, g = L*2+half. hw blockIdx = 8*(c>>1) + 2g + (c&1)
// so each group's 64 blocks land on 2 XCDs (blockIdx%8 round-robin heuristic;
// perf-only). Weights AGPR-pinned; 1 wave/SIMD -> program order = critical
// path, so the step is organized to minimize serial LLC round trips:
//   - per-wave flags (2/block), posted after that wave's own inline vmcnt(0);
//     no tail __syncthreads (red is double-buffered)
//   - consumers issue each 32-col h chunk's loads as soon as its 4 producer
//     flags flip (fine-grained ballot poll), x-MFMAs overlap the in-flight RTs
//   - L1 caches L0's min flag; the tail x-poll is usually free
//   - deferred out stores are PLAIN (L2 ack) so FIFO vmcnt never waits on HBM
template <int L>
__device__ __forceinline__ void run_layer(
    const u16* __restrict__ xin, const u16* __restrict__ wx, const u16* __restrict__ wh,
    const float* __restrict__ bias, u16* __restrict__ xs1, u16* __restrict__ h1b,
    const float* __restrict__ c0, const int* __restrict__ reset,
    float* __restrict__ out, int* __restrict__ flags, int half, int col0, int lb,
    f32x4* __restrict__ red, unsigned* __restrict__ rbits, float* __restrict__ lbias,
    const int s1mask, const int h1mask, const int full) {
  constexpr int KX   = L ? H : D;
  constexpr int NCX  = KX / 32;
  constexpr int NCXW = NCX / 4;        // x chunks per wave (4 or 8)
  constexpr int NHW  = (H / 32) / 4;   // h chunks per wave (8)
  constexpr int NCW  = NCXW + NHW;
  const size_t BH = (size_t)B * H;
  const size_t OUT_HN = (size_t)T * BH;
  const size_t OUT_CN = OUT_HN + 2 * BH;

  const int tid  = threadIdx.x;
  const int ks   = tid >> 6;
  const int lane = tid & 63;
  const int q    = lane >> 4;
  const int ln   = lane & 15;

  // ---- one-time LDS prep
  for (int t = tid; t < T; t += NTHR) {
    unsigned v = 0;
#pragma unroll 8
    for (int i = 0; i < 32; ++i)
      v |= (unsigned)(reset[t * B + half * BS + i] & 1) << i;
    rbits[t] = v;
  }
  if (tid < 64) lbias[tid] = bias[(tid >> 4) * H + col0 + (tid & 15)];

  // ---- weights -> AGPR
  u32x4 wreg[4][NCW];
#pragma unroll
  for (int g = 0; g < 4; ++g)
#pragma unroll
    for (int cc = 0; cc < NCW; ++cc) {
      const bool isx = cc < NCXW;
      const int c = isx ? ks * NCXW + cc : ks * NHW + (cc - NCXW);
      const u16* W = isx ? wx : wh;
      const int stride = isx ? KX : H;
      const int kk = c * 32 + q * 8;
      wreg[g][cc] = *reinterpret_cast<const u32x4*>(
          W + (size_t)(g * H + col0 + ln) * stride + kk);
    }
#pragma unroll
  for (int g = 0; g < 4; ++g)
#pragma unroll
    for (int cc = 0; cc < NCW; ++cc)
      asm volatile("" : "+a"(wreg[g][cc]));

  // ---- cell state
  const int b0l = (tid >> 4) * 4;
  const int cl  = col0 + (tid & 15);
  float creg[4] = {0.f, 0.f, 0.f, 0.f};
  if (tid < 128)
#pragma unroll
    for (int r = 0; r < 4; ++r)
      creg[r] = c0[(size_t)(half * BS + b0l + r) * 2 * H + (size_t)L * H + cl];

  __syncthreads();
  float bval[4];
#pragma unroll
  for (int g = 0; g < 4; ++g) bval[g] = lbias[g * 16 + (tid & 15)];

  // persistent x prefetch regs
  uint4 xf[NCXW][MT];
  auto load_xfrags = [&](const u16* xsrc) {
#pragma unroll
    for (int cc = 0; cc < NCXW; ++cc) {
      const int kk = (ks * NCXW + cc) * 32 + q * 8;
#pragma unroll
      for (int m = 0; m < MT; ++m)
        xf[cc][m] = *reinterpret_cast<const uint4*>(
            xsrc + (size_t)(half * BS + 16 * m + ln) * KX + kk);
    }
  };
  if (full && L == 0) load_xfrags(xin);   // t=0 prologue

  const int fbaseH = 2 * ((L * 2 + half) * 64 + ks * 16);  // own-group flags
  const int fbaseX = 2 * (half * 64 + ks * 16);            // L0 group (for L1 x)
  int l0seen = 0;

  for (int s = 0; s <= T; ++s) {
    const bool active = (L == 0) ? (s < T) : (s >= 1);
    const int t = (L == 0) ? s : s - 1;
    if (active) {
      const u16* hsrc = (L == 0) ? xs1 + (size_t)(s & s1mask) * BH
                                 : h1b + (size_t)(t & h1mask) * BH;
      uint4 hf[NHW][MT];
      unsigned issuedChunks = 0;

      auto pollIssue = [&]() {
        int fv = (lane < 32) ? ldflag(flags, fbaseH + lane) : 0x7fffffff;
        unsigned rdy = (unsigned)__ballot(fv >= s);
        asm volatile("" ::: "memory");   // loads below never hoist above the poll
        unsigned newly = 0;
#pragma unroll
        for (int cc = 0; cc < NHW; ++cc)
          if (((rdy >> (4 * cc)) & 0xFu) == 0xFu) newly |= 1u << cc;
        newly &= ~issuedChunks;
#pragma unroll
        for (int cc = 0; cc < NHW; ++cc)
          if ((newly >> cc) & 1u) {
            const int kk = (ks * NHW + cc) * 32 + q * 8;
            hf[cc][0] = *reinterpret_cast<const uint4*>(
                hsrc + (size_t)(half * BS + ln) * H + kk);
            hf[cc][1] = *reinterpret_cast<const uint4*>(
                hsrc + (size_t)(half * BS + 16 + ln) * H + kk);
          }
        issuedChunks |= newly;
      };

      if (full) {
        pollIssue();                      // issue whatever is already ready
      } else {
        // fallback: full-grid barrier + acquire fence, then burst everything
        while (ldflag(flags, tid) < s || ldflag(flags, 256 + tid) < s)
          __builtin_amdgcn_s_sleep(1);
        __syncthreads();
        if (tid == 0) __builtin_amdgcn_fence(__ATOMIC_ACQUIRE, "agent");
        __syncthreads();
        asm volatile("" ::: "memory");
        load_xfrags((L == 0) ? xin + (size_t)t * B * D
                             : xs1 + (size_t)(s & s1mask) * BH);
#pragma unroll
        for (int cc = 0; cc < NHW; ++cc) {
          const int kk = (ks * NHW + cc) * 32 + q * 8;
          hf[cc][0] = *reinterpret_cast<const uint4*>(
              hsrc + (size_t)(half * BS + ln) * H + kk);
          hf[cc][1] = *reinterpret_cast<const uint4*>(
              hsrc + (size_t)(half * BS + 16 + ln) * H + kk);
        }
        issuedChunks = (1u << NHW) - 1u;
      }

      f32x4 acc[4][MT];
#pragma unroll
      for (int g = 0; g < 4; ++g)
#pragma unroll
        for (int m = 0; m < MT; ++m) acc[g][m] = (f32x4){0.f, 0.f, 0.f, 0.f};

      // x MFMAs from prefetched regs (cover in-flight h loads / stragglers)
#pragma unroll
      for (int cc = 0; cc < NCXW; ++cc)
#pragma unroll
        for (int g = 0; g < 4; ++g)
#pragma unroll
          for (int m = 0; m < MT; ++m)
            acc[g][m] = mfma16(__builtin_bit_cast(bf16x8, xf[cc][m]),
                               __builtin_bit_cast(bf16x8, wreg[g][cc]), acc[g][m]);

      if (full)
        while (issuedChunks != (1u << NHW) - 1u) {
          __builtin_amdgcn_s_sleep(1);
          pollIssue();
        }

      // h MFMAs (reset zeroes recurrent rows)
      const unsigned rw = rbits[t];
      const int rz0 = (int)((rw >> ln) & 1u);
      const int rz1 = (int)((rw >> (16 + ln)) & 1u);
      const uint4 zz = make_uint4(0u, 0u, 0u, 0u);
#pragma unroll
      for (int cc = 0; cc < NHW; ++cc) {
        const uint4 v0 = rz0 ? zz : hf[cc][0];
        const uint4 v1 = rz1 ? zz : hf[cc][1];
#pragma unroll
        for (int g = 0; g < 4; ++g) {
          acc[g][0] = mfma16(__builtin_bit_cast(bf16x8, v0),
                             __builtin_bit_cast(bf16x8, wreg[g][NCXW + cc]), acc[g][0]);
          acc[g][1] = mfma16(__builtin_bit_cast(bf16x8, v1),
                             __builtin_bit_cast(bf16x8, wreg[g][NCXW + cc]), acc[g][1]);
        }
      }

      // dump partials into the step-parity red buffer (no tail sync needed)
      f32x4* rbuf = red + (size_t)(s & 1) * (16 * 128);
#pragma unroll
      for (int g = 0; g < 4; ++g)
#pragma unroll
        for (int m = 0; m < MT; ++m)
          rbuf[(g * 4 + ks) * 128 + m * 64 + lane] = acc[g][m];
      __syncthreads();   // the ONE per-step rendezvous

      if (tid < 128) {
        f32x4 gate[4];
#pragma unroll
        for (int g = 0; g < 4; ++g) {
          f32x4 sum = rbuf[(g * 4 + 0) * 128 + tid];
#pragma unroll
          for (int w = 1; w < 4; ++w) sum += rbuf[(g * 4 + w) * 128 + tid];
          gate[g] = sum + (f32x4){bval[g], bval[g], bval[g], bval[g]};
        }
        const unsigned rstw = rbits[t] >> b0l;
        float hv[4];
        u16 hb[4];
#pragma unroll
        for (int r = 0; r < 4; ++r) {
          float cp = ((rstw >> r) & 1u) ? 0.f : creg[r];
          float i_ = sigm(gate[0][r]);
          float f_ = sigm(gate[1][r]);
          float g_ = tanhfast(gate[2][r]);
          float o_ = sigm(gate[3][r]);
          float cn = fmaf(f_, cp, i_ * g_);
          float hn = o_ * tanhfast(cn);
          creg[r] = cn;
          hv[r] = hn;
          hb[r] = f2bf(hn);
        }
        if (s < T) {   // publish h (skipped on L1's final step: nobody reads it)
          u16* hdst = (L == 0)
              ? xs1 + (size_t)((s + 1) & s1mask) * BH
              : h1b + (size_t)((t + 1) & h1mask) * BH;
#pragma unroll
          for (int r = 0; r < 4; ++r) {
            unsigned own = hb[r];
            unsigned oth = (unsigned)__shfl_xor((int)own, 1);
            unsigned pk = (tid & 1) ? ((oth & 0xffffu) | (own << 16))
                                    : (own | (oth << 16));
            if ((r >> 1) == (tid & 1))
              __hip_atomic_store(
                  reinterpret_cast<unsigned*>(
                      hdst + (size_t)(half * BS + b0l + r) * H + (cl & ~1)),
                  pk, __ATOMIC_RELAXED, __HIP_MEMORY_SCOPE_AGENT);
          }
        }
        if (t == T - 1) {
#pragma unroll
          for (int r = 0; r < 4; ++r) {
            const size_t brow = (size_t)(half * BS + b0l + r);
            __builtin_nontemporal_store(
                hv[r], &out[OUT_HN + brow * 2 * H + (size_t)L * H + cl]);
            __builtin_nontemporal_store(
                creg[r], &out[OUT_CN + brow * 2 * H + (size_t)L * H + cl]);
            if (L == 1)
              __builtin_nontemporal_store(
                  hv[r], &out[(size_t)t * BH + brow * H + cl]);
          }
        }
        if (full && s < T) {
          // per-wave drain + flag: this wave's publishes are at LLC
          asm volatile("s_waitcnt vmcnt(0)" ::: "memory");
          if (lane == 0)
            __hip_atomic_store(&flags[2 * lb + (tid >> 6)], s + 1,
                               __ATOMIC_RELAXED, __HIP_MEMORY_SCOPE_AGENT);
        }
        if (L == 1 && t < T - 1) {   // deferred out rows: PLAIN stores (L2 ack)
#pragma unroll
          for (int r = 0; r < 4; ++r)
            out[(size_t)t * BH + (size_t)(half * BS + b0l + r) * H + cl] = hv[r];
        }
      }
    }

    // ---- tail: next-step x prefetch (off critical path)
    if (s < T) {
      if (full) {
        if (L == 0) {
          if (s + 1 < T) load_xfrags(xin + (size_t)(s + 1) * B * D);
        } else {
          if (l0seen <= s) {   // need L0 >= s+1; usually cached (L0 runs ahead)
            for (;;) {
              int fv = (lane < 32) ? ldflag(flags, fbaseX + lane) : 0x7fffffff;
              int mn = fv;
#pragma unroll
              for (int o = 1; o < 64; o <<= 1) mn = min(mn, __shfl_xor(mn, o));
              l0seen = mn;
              if (l0seen >= s + 1) break;
              __builtin_amdgcn_s_sleep(1);
            }
            asm volatile("" ::: "memory");
          }
          load_xfrags(xs1 + (size_t)((s + 1) & s1mask) * BH);
        }
      } else {
        __syncthreads();   // fallback: drain all, then single flag pair
        if (tid == 0) {
          __hip_atomic_store(&flags[2 * lb], s + 1,
                             __ATOMIC_RELAXED, __HIP_MEMORY_SCOPE_AGENT);
          __hip_atomic_store(&flags[2 * lb + 1], s + 1,
                             __ATOMIC_RELAXED, __HIP_MEMORY_SCOPE_AGENT);
        }
      }
    }
  }
}

__global__ void __launch_bounds__(NTHR, 1) lstm_seq(
    const u16* __restrict__ xin,
    const u16* __restrict__ wx0, const u16* __restrict__ wh0,
    const u16* __restrict__ wx1, const u16* __restrict__ wh1,
    const float* __restrict__ bias0, const float* __restrict__ bias1,
    u16* __restrict__ xs1, u16* __restrict__ h1b,
    const float* __restrict__ c0, const int* __restrict__ reset,
    float* __restrict__ out, int* __restrict__ flags,
    int s1mask, int h1mask, int full) {
  __shared__ f32x4 red[2 * 16 * 128];     // 64 KB partials, step-parity dbuf
  __shared__ unsigned rbits[T];           // packed reset bits (this half)
  __shared__ float lbias[64];
  // hw blockIdx -> (g, c): g on XCDs {2g,2g+1} under the %8 round-robin heuristic
  const int g    = (blockIdx.x & 7) >> 1;
  const int c    = ((blockIdx.x >> 3) << 1) | (blockIdx.x & 1);
  const int half = g & 1;
  const int col0 = c << 4;
  const int lb   = g * 64 + c;
  if ((g >> 1) == 0)
    run_layer<0>(xin, wx0, wh0, bias0, xs1, h1b, c0, reset, out, flags, half, col0, lb,
                 red, rbits, lbias, s1mask, h1mask, full);
  else
    run_layer<1>(nullptr, wx1, wh1, bias1, xs1, h1b, c0, reset, out, flags, half, col0, lb,
                 red, rbits, lbias, s1mask, h1mask, full);
}

extern "C" void kernel_launch(void* const* d_in, const int* in_sizes, int n_in,
                              void* d_out, int out_size, void* d_ws, size_t ws_size,
                              hipStream_t stream) {
  (void)in_sizes; (void)n_in; (void)out_size;
  const float* input = (const float*)d_in[0];
  const int*   reset = (const int*)d_in[1];
  const float* h0    = (const float*)d_in[2];
  const float* c0    = (const float*)d_in[3];
  const float* Wih0  = (const float*)d_in[4];
  const float* Whh0  = (const float*)d_in[5];
  const float* bih0  = (const float*)d_in[6];
  const float* bhh0  = (const float*)d_in[7];
  const float* Wih1  = (const float*)d_in[8];
  const float* Whh1  = (const float*)d_in[9];
  const float* bih1  = (const float*)d_in[10];
  const float* bhh1  = (const float*)d_in[11];
  float* out = (float*)d_out;
  char* ws = (char*)d_ws;

  const size_t SLOT = (size_t)B * H * 2;
  const size_t FIXED = (size_t)G4 * D * 2 + 3 * (size_t)G4 * H * 2
                     + (size_t)T * B * D * 2
                     + 2 * (size_t)G4 * 4 + 8192;
  const bool full = ws_size >= FIXED + 2 * (size_t)(T + 1) * SLOT + 65536;
  const int d0 = full ? (T + 1) : 4;
  const int d1 = full ? (T + 1) : 2;
  const int s1mask = full ? 511 : 3;
  const int h1mask = full ? 511 : 1;

  size_t off = 0;
  auto alloc = [&](size_t bytes) { size_t o = off; off += (bytes + 255) & ~(size_t)255; return o; };
  u16* wx0 = (u16*)(ws + alloc((size_t)G4 * D * 2));
  u16* wh0 = (u16*)(ws + alloc((size_t)G4 * H * 2));
  u16* wx1 = (u16*)(ws + alloc((size_t)G4 * H * 2));
  u16* wh1 = (u16*)(ws + alloc((size_t)G4 * H * 2));
  u16* xin = (u16*)(ws + alloc((size_t)T * B * D * 2));
  u16* xs1 = (u16*)(ws + alloc((size_t)d0 * SLOT));
  u16* h1b = (u16*)(ws + alloc((size_t)d1 * SLOT));
  float* pb0 = (float*)(ws + alloc((size_t)G4 * 4));
  float* pb1 = (float*)(ws + alloc((size_t)G4 * 4));
  int* flg = (int*)(ws + alloc(2048));

  cvt_bf16<<<1024, 256, 0, stream>>>(Wih0, wx0, G4 * D / 4);
  cvt_bf16<<<1024, 256, 0, stream>>>(Whh0, wh0, G4 * H / 4);
  cvt_bf16<<<1024, 256, 0, stream>>>(Wih1, wx1, G4 * H / 4);
  cvt_bf16<<<1024, 256, 0, stream>>>(Whh1, wh1, G4 * H / 4);
  cvt_bf16<<<2048, 256, 0, stream>>>(input, xin, T * B * D / 4);
  init_state<<<512, 256, 0, stream>>>(h0, xs1, h1b, bih0, bhh0, bih1, bhh1, pb0, pb1, flg);
  lstm_seq<<<NBLK, NTHR, 0, stream>>>(xin, wx0, wh0, wx1, wh1, pb0, pb1,
                                      xs1, h1b, c0, reset, out, flg,
                                      s1mask, h1mask, full ? 1 : 0);
}

// Round 6
// 1816.911 us; speedup vs baseline: 1.2901x; 1.2901x over previous
//
#include <hip/hip_runtime.h>

typedef __bf16 bf16x8 __attribute__((ext_vector_type(8)));
typedef float f32x4 __attribute__((ext_vector_type(4)));
typedef unsigned u32x4 __attribute__((ext_vector_type(4)));
typedef unsigned short u16;

constexpr int T = 256, B = 64, D = 512, H = 1024;
constexpr int G4 = 4 * H;
constexpr int NBLK = 256;   // 2 layers x 2 batch-halves x 64 col-blocks (1/CU)
constexpr int NTHR = 256;   // 4 waves; wave = one K-quarter, all 4 gates
constexpr int BS = 32;      // batches per block
constexpr int MT = 2;       // 16-row MFMA tiles per block

__device__ __forceinline__ u16 f2bf(float f) {
  unsigned u = __builtin_bit_cast(unsigned, f);
  u += 0x7fffu + ((u >> 16) & 1u);
  return (u16)(u >> 16);
}

__device__ __forceinline__ f32x4 mfma16(bf16x8 a, bf16x8 b, f32x4 c) {
  return __builtin_amdgcn_mfma_f32_16x16x32_bf16(a, b, c, 0, 0, 0);
}

__device__ __forceinline__ float sigm(float x) { return 1.f / (1.f + expf(-x)); }

__device__ __forceinline__ int ldflag(const int* f, int i) {
  return __hip_atomic_load(&f[i], __ATOMIC_RELAXED, __HIP_MEMORY_SCOPE_AGENT);
}

// ---------------- prep kernels ----------------
__global__ void cvt_bf16(const float* __restrict__ src, u16* __restrict__ dst, int n4) {
  int i = blockIdx.x * blockDim.x + threadIdx.x;
  int st = gridDim.x * blockDim.x;
  for (; i < n4; i += st) {
    float4 v = reinterpret_cast<const float4*>(src)[i];
    ushort4 o;
    o.x = f2bf(v.x); o.y = f2bf(v.y); o.z = f2bf(v.z); o.w = f2bf(v.w);
    reinterpret_cast<ushort4*>(dst)[i] = o;
  }
}

__global__ void init_state(const float* __restrict__ h0,
                           u16* __restrict__ xs1, u16* __restrict__ h1buf,
                           const float* __restrict__ bih0, const float* __restrict__ bhh0,
                           const float* __restrict__ bih1, const float* __restrict__ bhh1,
                           float* __restrict__ bias0, float* __restrict__ bias1,
                           int* __restrict__ flags) {
  int i = blockIdx.x * blockDim.x + threadIdx.x;
  if (i < NBLK) flags[i] = 0;              // per-block step flags (replay-safe reset)
  if (i < 2 * B * H) {
    int l = i / (B * H), rem = i % (B * H);
    int b = rem / H, k = rem % H;
    u16 v = f2bf(h0[(size_t)b * 2 * H + (size_t)l * H + k]);
    if (l == 0) xs1[(size_t)b * H + k] = v;   // slot 0 = initial h for layer0
    else        h1buf[(size_t)b * H + k] = v; // slot 0 = initial h for layer1
  }
  if (i < G4) {
    bias0[i] = bih0[i] + bhh0[i];
    bias1[i] = bih1[i] + bhh1[i];
  }
}

// ---------------- persistent pipelined LSTM ----------------
// Logical block lb = g*64 + c, g = L*2+half; hw blockIdx = 8*(c>>1) + 2g + (c&1)
// -> each group's 64 blocks land on 2 XCDs (L2 sharing of the group's h slab;
// FETCH 451->152 MB measured). Weights AGPR-pinned; 1 wave/SIMD -> program
// order = critical path; schedule minimizes serial LLC round trips:
//   head : poll ONLY the 16 own-quarter producer flags -> burst all h loads
//          -> x MFMAs from prefetched regs (cover h RT) -> h MFMAs
//   tail : block sync (vmcnt drain) -> 1 flag/block -> plain out stores
//          -> next-step x prefetch (L1: cached L0-min, poll usually free)
// Coherence: monotonic h history + write-through agent stores; lines fetched
// only after the producer's flag can't be stale -> PLAIN loads, no fences.
template <int L>
__device__ __forceinline__ void run_layer(
    const u16* __restrict__ xin, const u16* __restrict__ wx, const u16* __restrict__ wh,
    const float* __restrict__ bias, u16* __restrict__ xs1, u16* __restrict__ h1b,
    const float* __restrict__ c0, const int* __restrict__ reset,
    float* __restrict__ out, int* __restrict__ flags, int half, int col0, int lb,
    f32x4* __restrict__ red, unsigned* __restrict__ rbits, float* __restrict__ lbias,
    const int s1mask, const int h1mask, const int full) {
  constexpr int KX   = L ? H : D;
  constexpr int NCX  = KX / 32;
  constexpr int NCXW = NCX / 4;        // x chunks per wave (4 or 8)
  constexpr int NHW  = (H / 32) / 4;   // h chunks per wave (8)
  constexpr int NCW  = NCXW + NHW;
  const size_t BH = (size_t)B * H;
  const size_t OUT_HN = (size_t)T * BH;
  const size_t OUT_CN = OUT_HN + 2 * BH;

  const int tid  = threadIdx.x;
  const int ks   = tid >> 6;
  const int lane = tid & 63;
  const int q    = lane >> 4;
  const int ln   = lane & 15;

  // ---- one-time LDS prep
  for (int t = tid; t < T; t += NTHR) {
    unsigned v = 0;
#pragma unroll 8
    for (int i = 0; i < 32; ++i)
      v |= (unsigned)(reset[t * B + half * BS + i] & 1) << i;
    rbits[t] = v;
  }
  if (tid < 64) lbias[tid] = bias[(tid >> 4) * H + col0 + (tid & 15)];

  // ---- weights -> AGPR (pinned; VGPRs stay free for load pipelining)
  u32x4 wreg[4][NCW];
#pragma unroll
  for (int g = 0; g < 4; ++g)
#pragma unroll
    for (int cc = 0; cc < NCW; ++cc) {
      const bool isx = cc < NCXW;
      const int c = isx ? ks * NCXW + cc : ks * NHW + (cc - NCXW);
      const u16* W = isx ? wx : wh;
      const int stride = isx ? KX : H;
      const int kk = c * 32 + q * 8;
      wreg[g][cc] = *reinterpret_cast<const u32x4*>(
          W + (size_t)(g * H + col0 + ln) * stride + kk);
    }
#pragma unroll
  for (int g = 0; g < 4; ++g)
#pragma unroll
    for (int cc = 0; cc < NCW; ++cc)
      asm volatile("" : "+a"(wreg[g][cc]));

  // ---- cell state: thread (tid<128) owns batches b0l..b0l+3, col cl
  const int b0l = (tid >> 4) * 4;
  const int cl  = col0 + (tid & 15);
  float creg[4] = {0.f, 0.f, 0.f, 0.f};
  if (tid < 128)
#pragma unroll
    for (int r = 0; r < 4; ++r)
      creg[r] = c0[(size_t)(half * BS + b0l + r) * 2 * H + (size_t)L * H + cl];

  __syncthreads();
  float bval[4];
#pragma unroll
  for (int g = 0; g < 4; ++g) bval[g] = lbias[g * 16 + (tid & 15)];

  float hv[4] = {0.f, 0.f, 0.f, 0.f};

  // persistent x prefetch regs (unconditional loads only -> fixed registers)
  uint4 xf[NCXW][MT];
  auto load_xfrags = [&](const u16* xsrc) {
#pragma unroll
    for (int cc = 0; cc < NCXW; ++cc) {
      const int kk = (ks * NCXW + cc) * 32 + q * 8;
#pragma unroll
      for (int m = 0; m < MT; ++m)
        xf[cc][m] = *reinterpret_cast<const uint4*>(
            xsrc + (size_t)(half * BS + 16 * m + ln) * KX + kk);
    }
  };
  if (full && L == 0) load_xfrags(xin);   // t=0 prologue

  const int gbase = (L * 2 + half) * 64 + ks * 16;  // own-quarter producer flags
  const int xbase = half * 64 + ks * 16;            // L0 group (L1's x source)
  int l0seen = 0;

  for (int s = 0; s <= T; ++s) {
    const bool active = (L == 0) ? (s < T) : (s >= 1);
    const int t = (L == 0) ? s : s - 1;
    if (active) {
      const u16* hsrc = (L == 0) ? xs1 + (size_t)(s & s1mask) * BH
                                 : h1b + (size_t)(t & h1mask) * BH;
      if (full) {
        // own-quarter h poll: 16 flags, all 64 lanes (lane&15 broadcast)
        while (ldflag(flags, gbase + (lane & 15)) < s) __builtin_amdgcn_s_sleep(1);
        asm volatile("" ::: "memory");
      } else {
        // fallback: full-grid barrier + acquire fence, then x in-loop
        for (;;) {
          int a = ldflag(flags, lane),       b = ldflag(flags, 64 + lane);
          int c = ldflag(flags, 128 + lane), d = ldflag(flags, 192 + lane);
          int m1 = a < b ? a : b, m2 = c < d ? c : d;
          if ((m1 < m2 ? m1 : m2) >= s) break;
          __builtin_amdgcn_s_sleep(1);
        }
        __builtin_amdgcn_fence(__ATOMIC_ACQUIRE, "agent");   // buffer_inv
        asm volatile("" ::: "memory");
        load_xfrags((L == 0) ? xin + (size_t)t * B * D
                             : xs1 + (size_t)(s & s1mask) * BH);
      }

      // ---- BURST all h fragment loads (unconditional -> fixed regs)
      uint4 hf[NHW][MT];
#pragma unroll
      for (int cc = 0; cc < NHW; ++cc) {
        const int kk = (ks * NHW + cc) * 32 + q * 8;
#pragma unroll
        for (int m = 0; m < MT; ++m)
          hf[cc][m] = *reinterpret_cast<const uint4*>(
              hsrc + (size_t)(half * BS + 16 * m + ln) * H + kk);
      }

      f32x4 acc[4][MT];
#pragma unroll
      for (int g = 0; g < 4; ++g)
#pragma unroll
        for (int m = 0; m < MT; ++m) acc[g][m] = (f32x4){0.f, 0.f, 0.f, 0.f};

      // ---- x MFMAs from prefetched regs (cover in-flight h loads)
#pragma unroll
      for (int cc = 0; cc < NCXW; ++cc)
#pragma unroll
        for (int g = 0; g < 4; ++g)
#pragma unroll
          for (int m = 0; m < MT; ++m)
            acc[g][m] = mfma16(__builtin_bit_cast(bf16x8, xf[cc][m]),
                               __builtin_bit_cast(bf16x8, wreg[g][cc]), acc[g][m]);

      // ---- h MFMAs (reset zeroes recurrent rows)
      const unsigned rw = rbits[t];
      const int rz0 = (int)((rw >> ln) & 1u);
      const int rz1 = (int)((rw >> (16 + ln)) & 1u);
      const uint4 zz = make_uint4(0u, 0u, 0u, 0u);
#pragma unroll
      for (int cc = 0; cc < NHW; ++cc) {
        const uint4 v0 = rz0 ? zz : hf[cc][0];
        const uint4 v1 = rz1 ? zz : hf[cc][1];
#pragma unroll
        for (int g = 0; g < 4; ++g) {
          acc[g][0] = mfma16(__builtin_bit_cast(bf16x8, v0),
                             __builtin_bit_cast(bf16x8, wreg[g][NCXW + cc]), acc[g][0]);
          acc[g][1] = mfma16(__builtin_bit_cast(bf16x8, v1),
                             __builtin_bit_cast(bf16x8, wreg[g][NCXW + cc]), acc[g][1]);
        }
      }

      // ---- dump partials: conflict-free ds_write_b128
#pragma unroll
      for (int g = 0; g < 4; ++g)
#pragma unroll
        for (int m = 0; m < MT; ++m)
          red[(g * 4 + ks) * (MT * 64) + m * 64 + lane] = acc[g][m];
      __syncthreads();

      // ---- reduce + cell update
      if (tid < 128) {
        f32x4 gate[4];
#pragma unroll
        for (int g = 0; g < 4; ++g) {
          f32x4 sum = red[(g * 4 + 0) * (MT * 64) + tid];
#pragma unroll
          for (int w = 1; w < 4; ++w) sum += red[(g * 4 + w) * (MT * 64) + tid];
          gate[g] = sum + (f32x4){bval[g], bval[g], bval[g], bval[g]};
        }
        const unsigned rstw = rbits[t] >> b0l;
        u16 hb[4];
#pragma unroll
        for (int r = 0; r < 4; ++r) {
          float cp = ((rstw >> r) & 1u) ? 0.f : creg[r];
          float i_ = sigm(gate[0][r]);
          float f_ = sigm(gate[1][r]);
          float g_ = tanhf(gate[2][r]);
          float o_ = sigm(gate[3][r]);
          float cn = fmaf(f_, cp, i_ * g_);
          float hn = o_ * tanhf(cn);
          creg[r] = cn;
          hv[r] = hn;
          hb[r] = f2bf(hn);
        }
        if (s < T) {   // publish h (skip L1's final step: nobody reads it)
          u16* hdst = (L == 0)
              ? xs1 + (size_t)((s + 1) & s1mask) * BH
              : h1b + (size_t)((t + 1) & h1mask) * BH;
#pragma unroll
          for (int r = 0; r < 4; ++r) {
            unsigned own = hb[r];
            unsigned oth = (unsigned)__shfl_xor((int)own, 1);
            unsigned pk = (tid & 1) ? ((oth & 0xffffu) | (own << 16))
                                    : (own | (oth << 16));
            if ((r >> 1) == (tid & 1))
              __hip_atomic_store(
                  reinterpret_cast<unsigned*>(
                      hdst + (size_t)(half * BS + b0l + r) * H + (cl & ~1)),
                  pk, __ATOMIC_RELAXED, __HIP_MEMORY_SCOPE_AGENT);
          }
        }
        if (t == T - 1) {
#pragma unroll
          for (int r = 0; r < 4; ++r) {
            const size_t brow = (size_t)(half * BS + b0l + r);
            __builtin_nontemporal_store(
                hv[r], &out[OUT_HN + brow * 2 * H + (size_t)L * H + cl]);
            __builtin_nontemporal_store(
                creg[r], &out[OUT_CN + brow * 2 * H + (size_t)L * H + cl]);
            if (L == 1)
              __builtin_nontemporal_store(
                  hv[r], &out[(size_t)t * BH + brow * H + cl]);
          }
        }
      }
    }

    // ---- tail: drain publish (block sync), post flag; then off critical path:
    // plain out stores (L2 ack only) + next-step x prefetch.
    if (s < T) {
      __syncthreads();   // vmcnt(0) per wave: h stores are at LLC
      if (tid == 0)
        __hip_atomic_store(&flags[lb], s + 1,
                           __ATOMIC_RELAXED, __HIP_MEMORY_SCOPE_AGENT);
      if (L == 1 && active && t < T - 1 && tid < 128) {
#pragma unroll
        for (int r = 0; r < 4; ++r)
          out[(size_t)t * BH + (size_t)(half * BS + b0l + r) * H + cl] = hv[r];
      }
      if (full) {
        if (L == 0) {
          if (s + 1 < T) load_xfrags(xin + (size_t)(s + 1) * B * D);
        } else {
          // x for step s+1 = xs1[s+1]: needs L0(half, quarter) >= s+1.
          // l0seen caches the min -> poll usually skipped (L0 runs ahead).
          if (l0seen < s + 1) {
            int fv;
            for (;;) {
              fv = ldflag(flags, xbase + (lane & 15));
              if (__all(fv >= s + 1)) break;
              __builtin_amdgcn_s_sleep(1);
            }
            int mn = fv;
#pragma unroll
            for (int o = 1; o < 64; o <<= 1) mn = min(mn, __shfl_xor(mn, o));
            l0seen = mn;
            asm volatile("" ::: "memory");
          }
          load_xfrags(xs1 + (size_t)((s + 1) & s1mask) * BH);
        }
      }
    }
  }
}

__global__ void __launch_bounds__(NTHR, 1) lstm_seq(
    const u16* __restrict__ xin,
    const u16* __restrict__ wx0, const u16* __restrict__ wh0,
    const u16* __restrict__ wx1, const u16* __restrict__ wh1,
    const float* __restrict__ bias0, const float* __restrict__ bias1,
    u16* __restrict__ xs1, u16* __restrict__ h1b,
    const float* __restrict__ c0, const int* __restrict__ reset,
    float* __restrict__ out, int* __restrict__ flags,
    int s1mask, int h1mask, int full) {
  __shared__ f32x4 red[4 * 4 * MT * 64];  // 32 KB partials
  __shared__ unsigned rbits[T];           // packed reset bits (this half)
  __shared__ float lbias[64];
  // hw blockIdx -> (g, c): group g on XCDs {2g, 2g+1} (%8 round-robin heuristic)
  const int g    = (blockIdx.x & 7) >> 1;
  const int c    = ((blockIdx.x >> 3) << 1) | (blockIdx.x & 1);
  const int half = g & 1;
  const int col0 = c << 4;
  const int lb   = g * 64 + c;
  if ((g >> 1) == 0)
    run_layer<0>(xin, wx0, wh0, bias0, xs1, h1b, c0, reset, out, flags, half, col0, lb,
                 red, rbits, lbias, s1mask, h1mask, full);
  else
    run_layer<1>(nullptr, wx1, wh1, bias1, xs1, h1b, c0, reset, out, flags, half, col0, lb,
                 red, rbits, lbias, s1mask, h1mask, full);
}

extern "C" void kernel_launch(void* const* d_in, const int* in_sizes, int n_in,
                              void* d_out, int out_size, void* d_ws, size_t ws_size,
                              hipStream_t stream) {
  (void)in_sizes; (void)n_in; (void)out_size;
  const float* input = (const float*)d_in[0];
  const int*   reset = (const int*)d_in[1];
  const float* h0    = (const float*)d_in[2];
  const float* c0    = (const float*)d_in[3];
  const float* Wih0  = (const float*)d_in[4];
  const float* Whh0  = (const float*)d_in[5];
  const float* bih0  = (const float*)d_in[6];
  const float* bhh0  = (const float*)d_in[7];
  const float* Wih1  = (const float*)d_in[8];
  const float* Whh1  = (const float*)d_in[9];
  const float* bih1  = (const float*)d_in[10];
  const float* bhh1  = (const float*)d_in[11];
  float* out = (float*)d_out;
  char* ws = (char*)d_ws;

  const size_t SLOT = (size_t)B * H * 2;
  const size_t FIXED = (size_t)G4 * D * 2 + 3 * (size_t)G4 * H * 2
                     + (size_t)T * B * D * 2
                     + 2 * (size_t)G4 * 4 + 8192;
  const bool full = ws_size >= FIXED + 2 * (size_t)(T + 1) * SLOT + 65536;
  const int d0 = full ? (T + 1) : 4;
  const int d1 = full ? (T + 1) : 2;
  const int s1mask = full ? 511 : 3;
  const int h1mask = full ? 511 : 1;

  size_t off = 0;
  auto alloc = [&](size_t bytes) { size_t o = off; off += (bytes + 255) & ~(size_t)255; return o; };
  u16* wx0 = (u16*)(ws + alloc((size_t)G4 * D * 2));
  u16* wh0 = (u16*)(ws + alloc((size_t)G4 * H * 2));
  u16* wx1 = (u16*)(ws + alloc((size_t)G4 * H * 2));
  u16* wh1 = (u16*)(ws + alloc((size_t)G4 * H * 2));
  u16* xin = (u16*)(ws + alloc((size_t)T * B * D * 2));
  u16* xs1 = (u16*)(ws + alloc((size_t)d0 * SLOT));
  u16* h1b = (u16*)(ws + alloc((size_t)d1 * SLOT));
  float* pb0 = (float*)(ws + alloc((size_t)G4 * 4));
  float* pb1 = (float*)(ws + alloc((size_t)G4 * 4));
  int* flg = (int*)(ws + alloc(1024));

  cvt_bf16<<<1024, 256, 0, stream>>>(Wih0, wx0, G4 * D / 4);
  cvt_bf16<<<1024, 256, 0, stream>>>(Whh0, wh0, G4 * H / 4);
  cvt_bf16<<<1024, 256, 0, stream>>>(Wih1, wx1, G4 * H / 4);
  cvt_bf16<<<1024, 256, 0, stream>>>(Whh1, wh1, G4 * H / 4);
  cvt_bf16<<<2048, 256, 0, stream>>>(input, xin, T * B * D / 4);
  init_state<<<512, 256, 0, stream>>>(h0, xs1, h1b, bih0, bhh0, bih1, bhh1, pb0, pb1, flg);
  lstm_seq<<<NBLK, NTHR, 0, stream>>>(xin, wx0, wh0, wx1, wh1, pb0, pb1,
                                      xs1, h1b, c0, reset, out, flg,
                                      s1mask, h1mask, full ? 1 : 0);
}